// Round 1
// baseline (507.735 us; speedup 1.0000x reference)
//
#include <hip/hip_runtime.h>

// PixelWiseRNN: h_t = tanh(w_ih*x_t + (b_ih+b_hh) + w_hh*h_{t-1}), h_0 = 0
// x, out: (B=4, T=256, Z=16, H=64, W=64) fp32. Params: (Z,H,W) fp32.
//
// 262,144 independent scalar recurrences. Memory-bound: 512 MB R+W -> ~81 us
// roofline at 6.3 TB/s. One thread per 4 contiguous pixels (float4 lane
// loads), sequential t-loop with 2-deep prefetch (x addresses independent of
// the recurrence, so loads pipeline ahead of the tanh chain).

#define RNN_B 4
#define RNN_T 256
#define RNN_ZHW 65536            // 16*64*64
#define RNN_PG (RNN_ZHW / 4)     // pixel-groups (float4) per batch image: 16384

__global__ __launch_bounds__(256) void pixel_rnn_kernel(
    const float* __restrict__ x,
    const float* __restrict__ w_ih,
    const float* __restrict__ w_hh,
    const float* __restrict__ b_ih,
    const float* __restrict__ b_hh,
    float* __restrict__ out)
{
    const int g  = blockIdx.x * 256 + threadIdx.x;  // [0, B*PG) = [0, 65536)
    const int b  = g >> 14;                          // g / RNN_PG
    const int pg = g & (RNN_PG - 1);                 // pixel-group within image
    const int p  = pg << 2;                          // first pixel (float) index

    // Per-pixel parameters (independent of b; tiny, L2-resident).
    const float4 wi = *(const float4*)(w_ih + p);
    const float4 wh = *(const float4*)(w_hh + p);
    const float4 bi = *(const float4*)(b_ih + p);
    const float4 bh = *(const float4*)(b_hh + p);
    float4 bias;
    bias.x = bi.x + bh.x;
    bias.y = bi.y + bh.y;
    bias.z = bi.z + bh.z;
    bias.w = bi.w + bh.w;

    // Base pointers for this (b, pixel-group). Stride between consecutive t
    // is RNN_PG float4s. Blocks never straddle b (16384 % 256 == 0), so every
    // wave's 64 lanes load 64 contiguous float4s -> fully coalesced.
    const float4* __restrict__ xp = (const float4*)x + (size_t)b * (RNN_T * RNN_PG) + pg;
    float4* __restrict__ op       = (float4*)out     + (size_t)b * (RNN_T * RNN_PG) + pg;

    float4 h;
    h.x = 0.f; h.y = 0.f; h.z = 0.f; h.w = 0.f;

    // 2-deep rotating prefetch: xa = x_t, xb = x_{t+1}; issue x_{t+2} each
    // iteration (clamped index — uniform select, no divergence, no OOB).
    float4 xa = xp[0];
    float4 xb = xp[RNN_PG];

    for (int t = 0; t < RNN_T; ++t) {
        const float4 xc = xa;
        xa = xb;
        int tn = t + 2;
        tn = tn < RNN_T ? tn : RNN_T - 1;
        xb = xp[(size_t)tn * RNN_PG];

        h.x = tanhf(fmaf(wi.x, xc.x, fmaf(wh.x, h.x, bias.x)));
        h.y = tanhf(fmaf(wi.y, xc.y, fmaf(wh.y, h.y, bias.y)));
        h.z = tanhf(fmaf(wi.z, xc.z, fmaf(wh.z, h.z, bias.z)));
        h.w = tanhf(fmaf(wi.w, xc.w, fmaf(wh.w, h.w, bias.w)));

        op[(size_t)t * RNN_PG] = h;
    }
}

extern "C" void kernel_launch(void* const* d_in, const int* in_sizes, int n_in,
                              void* d_out, int out_size, void* d_ws, size_t ws_size,
                              hipStream_t stream) {
    const float* x    = (const float*)d_in[0];
    const float* w_ih = (const float*)d_in[1];
    const float* w_hh = (const float*)d_in[2];
    const float* b_ih = (const float*)d_in[3];
    const float* b_hh = (const float*)d_in[4];
    float* out        = (float*)d_out;

    // B*PG = 65536 threads -> 256 blocks x 256 threads (1 block/CU).
    pixel_rnn_kernel<<<dim3(RNN_B * RNN_PG / 256), dim3(256), 0, stream>>>(
        x, w_ih, w_hh, b_ih, b_hh, out);
}

// Round 3
// 427.241 us; speedup vs baseline: 1.1884x; 1.1884x over previous
//
#include <hip/hip_runtime.h>

// PixelWiseRNN: h_t = tanh(w_ih*x_t + (b_ih+b_hh) + w_hh*h_{t-1}), h_0 = 0
// x, out: (B=4, T=256, Z=16, H=64, W=64) fp32. Params: (Z,H,W) fp32.
//
// R1 post-mortem: 209 us, 1.9 TB/s, VALUBusy 25%, Occ 11% -> latency-bound.
//   - 1 wave/SIMD (65536 threads) + 2-deep prefetch = ~2 KB in flight/wave,
//     vs ~9 KB/CU needed at ~900 cyc HBM latency.
//   - tanhf costs ~53 us of VALU time (library expansion).
// R2: float2/thread (131072 threads -> 8 waves/CU), 8-deep rotating prefetch
//     (32 KB/CU outstanding), exp2-based tanh (5 VALU), nontemporal x/out
//     (out is never re-read; keep LLC for x).
// R2 fix: __builtin_nontemporal_* rejects HIP_vector_type float2 -> use a
//     native clang ext_vector_type(2) float.

#define RNN_B   4
#define RNN_T   256
#define RNN_ZHW 65536                 // 16*64*64
#define RNN_PG2 (RNN_ZHW / 2)         // float2 groups per image: 32768
#define PF_D    8                     // prefetch depth (T % PF_D == 0)

typedef float f32x2 __attribute__((ext_vector_type(2)));

__device__ __forceinline__ float fast_tanh(float x) {
    // tanh(x) = 1 - 2/(exp(2x)+1), exp(2x) = 2^(2*log2(e)*x)
    // Saturation: x->+inf: exp->inf, rcp->0, result 1. x->-inf: exp->0, result -1.
    float e = __builtin_amdgcn_exp2f(x * 2.885390081777927f);
    float r = __builtin_amdgcn_rcpf(e + 1.0f);
    return fmaf(-2.0f, r, 1.0f);
}

__global__ __launch_bounds__(256) void pixel_rnn_kernel(
    const float* __restrict__ x,
    const float* __restrict__ w_ih,
    const float* __restrict__ w_hh,
    const float* __restrict__ b_ih,
    const float* __restrict__ b_hh,
    float* __restrict__ out)
{
    const int g  = blockIdx.x * 256 + threadIdx.x;   // [0, B*PG2) = [0, 131072)
    const int b  = g >> 15;                          // g / RNN_PG2
    const int pg = g & (RNN_PG2 - 1);                // float2-group within image
    const int p  = pg << 1;                          // first float index

    // Per-pixel parameters (1 MB total, L2/LLC-resident; normal cached loads).
    const f32x2 wi = *(const f32x2*)(w_ih + p);
    const f32x2 wh = *(const f32x2*)(w_hh + p);
    const f32x2 bi = *(const f32x2*)(b_ih + p);
    const f32x2 bh = *(const f32x2*)(b_hh + p);
    const float bias_x = bi.x + bh.x;
    const float bias_y = bi.y + bh.y;

    // Lanes are consecutive pg -> 512 B contiguous per wave load. Blocks never
    // straddle b (32768 % 256 == 0).
    const f32x2* __restrict__ xp = (const f32x2*)x + (size_t)b * (RNN_T * RNN_PG2) + pg;
    f32x2* __restrict__ op       = (f32x2*)out     + (size_t)b * (RNN_T * RNN_PG2) + pg;

    float hx = 0.f, hy = 0.f;

    // 8-deep rotating prefetch: buf[j] holds x_{t+j}; each unrolled step
    // consumes buf[j] and issues the load for t+j+PF_D (clamped; the few
    // redundant tail loads hit L2). 8 loads + stores in flight per wave.
    f32x2 buf[PF_D];
#pragma unroll
    for (int j = 0; j < PF_D; ++j)
        buf[j] = __builtin_nontemporal_load(xp + (size_t)j * RNN_PG2);

    for (int t = 0; t < RNN_T; t += PF_D) {
#pragma unroll
        for (int j = 0; j < PF_D; ++j) {
            const f32x2 xc = buf[j];
            int tn = t + j + PF_D;
            tn = tn < RNN_T ? tn : RNN_T - 1;
            buf[j] = __builtin_nontemporal_load(xp + (size_t)tn * RNN_PG2);

            hx = fast_tanh(fmaf(wi.x, xc.x, fmaf(wh.x, hx, bias_x)));
            hy = fast_tanh(fmaf(wi.y, xc.y, fmaf(wh.y, hy, bias_y)));

            f32x2 h2; h2.x = hx; h2.y = hy;
            __builtin_nontemporal_store(h2, op + (size_t)(t + j) * RNN_PG2);
        }
    }
}

extern "C" void kernel_launch(void* const* d_in, const int* in_sizes, int n_in,
                              void* d_out, int out_size, void* d_ws, size_t ws_size,
                              hipStream_t stream) {
    const float* x    = (const float*)d_in[0];
    const float* w_ih = (const float*)d_in[1];
    const float* w_hh = (const float*)d_in[2];
    const float* b_ih = (const float*)d_in[3];
    const float* b_hh = (const float*)d_in[4];
    float* out        = (float*)d_out;

    // B*PG2 = 131072 threads -> 512 blocks x 256 (2 blocks/CU, 8 waves/CU).
    pixel_rnn_kernel<<<dim3(RNN_B * RNN_PG2 / 256), dim3(256), 0, stream>>>(
        x, w_ih, w_hh, b_ih, b_hh, out);
}